// Round 7
// baseline (268.407 us; speedup 1.0000x reference)
//
#include <hip/hip_runtime.h>
#include <hip/hip_bf16.h>
#include <math.h>

#define N_NODES 50000
#define E0      800000
#define E_TOT   (E0 + N_NODES)
#define SCAP    512
#define NB_EDGE_C ((E_TOT + 255) / 256)

using bf16 = __hip_bfloat16;
typedef __attribute__((ext_vector_type(8))) short bfrag;   // 8 bf16 (4 VGPRs)
typedef __attribute__((ext_vector_type(4))) float ffrag;   // 4 fp32 acc

static __device__ __forceinline__ float bfu2f_lo(unsigned u){ return __uint_as_float(u << 16); }
static __device__ __forceinline__ float bfu2f_hi(unsigned u){ return __uint_as_float(u & 0xffff0000u); }

static __device__ __forceinline__ unsigned packbf(float a, float b){
    bf16 x = __float2bfloat16(a), y = __float2bfloat16(b);
    unsigned short ux = *reinterpret_cast<unsigned short*>(&x);
    unsigned short uy = *reinterpret_cast<unsigned short*>(&y);
    return ((unsigned)uy << 16) | ux;
}

// per-wave dtype detects (one coalesced load + ballot)
static __device__ __forceinline__ int detect_f32(const unsigned* xu){
    int lane = threadIdx.x & 63;
    unsigned ex = (xu[lane] >> 7) & 0xFF;
    return (__ballot(ex < 100 || ex > 140) != 0ULL);
}
static __device__ __forceinline__ int detect_i32(const int* ei){
    int lane = threadIdx.x & 63;
    return (__ballot(ei[2 * lane + 1] != 0) != 0ULL);
}

static __device__ __forceinline__ float ldany(const void* p, int i, int isf32){
    return isf32 ? ((const float*)p)[i] : __bfloat162float(((const bf16*)p)[i]);
}

static __device__ __forceinline__ int load_dst(const int* ei, int e, int is32){
    if (e >= E0) return e - E0;
    return is32 ? ei[E0 + e] : (int)((const long long*)ei)[E0 + e];
}
static __device__ __forceinline__ int load_src(const int* ei, int e, int is32){
    if (e >= E0) return e - E0;
    return is32 ? ei[e] : (int)((const long long*)ei)[e];
}

// ---------------- MERGED convert + count: one grid, block-range split.
// Blocks [0, NB_EDGE): edge counting (atomic-bound, starts immediately);
// blocks [NB_EDGE, ...): weight/vec/x conversion (HBM-streaming, backfills).
// The two halves stress different pipes -> true overlap vs serial launches.
// deg must be zeroed BEFORE this kernel (hipMemsetAsync in launch).
// vecf: b1 @0(128), bg @128(64), b3 @192(64), att_s @256(128), att_d @384(128)
__global__ void k_convert_count(const void* __restrict__ xv,
                          const void* W1, const void* Wg, const void* W3,
                          const void* b1, const void* bg, const void* b3,
                          const void* as_, const void* ad_,
                          bf16* __restrict__ W1p, bf16* __restrict__ Wgp,
                          bf16* __restrict__ W3r, float* __restrict__ vecf,
                          bf16* __restrict__ xb,
                          const int* __restrict__ ei, int* __restrict__ deg,
                          int2* __restrict__ pkrk){
    int blk = blockIdx.x, t = threadIdx.x;
    if (blk < NB_EDGE_C){                     // ---- count part ----
        int is32 = detect_i32(ei);
        int e = blk * 256 + t;
        if (e >= E_TOT) return;
        int dst = load_dst(ei, e, is32);
        int src = load_src(ei, e, is32);
        if ((unsigned)dst >= N_NODES || (unsigned)src >= N_NODES){
            pkrk[e] = make_int2(-1, 0);
            return;
        }
        int r = atomicAdd(&deg[dst], 1);
        pkrk[e] = make_int2((src << 16) | dst, r);
        return;
    }
    int b = blk - NB_EDGE_C;                  // ---- convert part ----
    int isf = detect_f32((const unsigned*)xv);
    if (b >= 148){
        int i = (b - 148) * 256 + t;               // quad index
        if (i < N_NODES * 32){
            if (isf){
                float4 v = ((const float4*)xv)[i];
                ((uint2*)xb)[i] = make_uint2(packbf(v.x, v.y), packbf(v.z, v.w));
            } else {
                ((uint2*)xb)[i] = ((const uint2*)xv)[i];   // already bf16: copy
            }
        }
        return;
    }
    if (b < 16){                              // W3 plain row-major copy: 4096 elems
        int dd = b * 256 + t;
        W3r[dd] = __float2bfloat16(ldany(W3, dd, isf));
    }
    else if (b < 18){
        int i = (b - 16) * 256 + t;     // 0..511
        float v;
        if      (i < 128) v = ldany(b1,  i,       isf);
        else if (i < 192) v = ldany(bg,  i - 128, isf);
        else if (i < 256) v = ldany(b3,  i - 192, isf);
        else if (i < 384) v = ldany(as_, i - 256, isf);
        else              v = ldany(ad_, i - 384, isf);
        vecf[i] = v;
    } else {
        int d = (b - 18) * 256 + t;          // 0..16383 per W, two Ws
        const void* Wsrc = (d < 16384) ? W1 : Wg;
        bf16* Wdst = (d < 16384) ? W1p : Wgp;
        int dd = d & 16383;
        int j  = dd & 7;
        int L  = (dd >> 3) & 63;
        int kc = (dd >> 9) & 3;
        int ct = dd >> 11;
        int k = kc * 32 + ((L >> 4) << 3) + j;
        int n = ct * 16 + (L & 15);
        Wdst[dd] = __float2bfloat16(ldany(Wsrc, k * 128 + n, isf));
    }
}

__global__ void k_scanA(const int* __restrict__ deg, int* __restrict__ tmp, int* __restrict__ blk){
    __shared__ int s[256];
    int t = threadIdx.x;
    int i = blockIdx.x * 256 + t;
    int v = (i < N_NODES) ? deg[i] : 0;
    s[t] = v; __syncthreads();
    for (int off = 1; off < 256; off <<= 1){
        int x = (t >= off) ? s[t - off] : 0;
        __syncthreads();
        s[t] += x;
        __syncthreads();
    }
    if (t == 255) blk[blockIdx.x] = s[255];
    if (i < N_NODES) tmp[i] = s[t] - v;
}

// scanC with inlined cross-block prefix (each block reduces blk[0..B-1] itself)
__global__ void k_scanC(int* __restrict__ row_ptr, const int* __restrict__ blk,
                        const int* __restrict__ deg, float* __restrict__ inv_sqrt,
                        int nb){
    __shared__ int s[256];
    int t = threadIdx.x;
    int B = blockIdx.x;
    s[t] = (t < nb && t < B) ? blk[t] : 0;
    __syncthreads();
    for (int off = 128; off; off >>= 1){
        if (t < off) s[t] += s[t + off];
        __syncthreads();
    }
    int base = s[0];
    int i = B * 256 + t;
    if (i < N_NODES){
        row_ptr[i] += base;
        int d = deg[i];
        inv_sqrt[i] = (d > 0) ? rsqrtf((float)d) : 0.0f;
    }
    if (i == 0) row_ptr[N_NODES] = E_TOT;
}

// fill: NO atomics, no int64 re-read; one streaming int2 read + one scattered
// int2 store per edge.
__global__ void k_fill(const int2* __restrict__ pkrk, const int* __restrict__ row_ptr,
                       const float* __restrict__ isq, int2* __restrict__ ecr){
    int e = blockIdx.x * blockDim.x + threadIdx.x;
    if (e >= E_TOT) return;
    int2 pr = pkrk[e];
    unsigned pk = (unsigned)pr.x;
    if (pk == 0xFFFFFFFFu) return;
    int dst = pk & 0xFFFF;
    int src = pk >> 16;
    int pos = row_ptr[dst] + pr.y;
    float c = isq[dst] * isq[src];
    ecr[pos] = make_int2(src, __float_as_int(c));
}

// ---------------- gather: Xa = A_hat x — 4-way split wave; uint4 loads ----------------
__global__ __launch_bounds__(256) void k_gather(
        const uint4* __restrict__ xb16, const int* __restrict__ rp,
        const int2* __restrict__ ecr, uint4* __restrict__ Xa16){
    __shared__ int   scsr[SCAP];
    __shared__ float scf[SCAP];
    int n0 = blockIdx.x * 4;
    int b0 = rp[n0];
    int stot = min(rp[n0 + 4] - b0, SCAP);
    for (int i = threadIdx.x; i < stot; i += 256){
        int2 ev = ecr[b0 + i];
        scsr[i] = ev.x;
        scf[i]  = __int_as_float(ev.y);
    }
    __syncthreads();

    int w = threadIdx.x >> 6, lane = threadIdx.x & 63;
    int q4 = lane >> 4, fz = lane & 15;
    int n = n0 + w;
    float a0=0,a1=0,a2=0,a3=0,a4=0,a5=0,a6=0,a7=0;
    int b = rp[n] - b0, e = rp[n + 1] - b0;
    int elim = min(e, stot);
    #pragma unroll 2
    for (int i = b + q4; i < elim; i += 4){
        int s = scsr[i];
        float c = scf[i];
        uint4 v = xb16[(size_t)s * 16 + fz];
        a0 += c * bfu2f_lo(v.x);  a1 += c * bfu2f_hi(v.x);
        a2 += c * bfu2f_lo(v.y);  a3 += c * bfu2f_hi(v.y);
        a4 += c * bfu2f_lo(v.z);  a5 += c * bfu2f_hi(v.z);
        a6 += c * bfu2f_lo(v.w);  a7 += c * bfu2f_hi(v.w);
    }
    int start = max(b, stot);
    int i0 = start + (((b + q4) - start) & 3);         // keep i ≡ b+q4 (mod 4)
    for (int i = i0; i < e; i += 4){                   // fallback (pathological degree)
        int2 ev = ecr[b0 + i];
        float c = __int_as_float(ev.y);
        uint4 v = xb16[(size_t)ev.x * 16 + fz];
        a0 += c * bfu2f_lo(v.x);  a1 += c * bfu2f_hi(v.x);
        a2 += c * bfu2f_lo(v.y);  a3 += c * bfu2f_hi(v.y);
        a4 += c * bfu2f_lo(v.z);  a5 += c * bfu2f_hi(v.z);
        a6 += c * bfu2f_lo(v.w);  a7 += c * bfu2f_hi(v.w);
    }
    a0 += __shfl_xor(a0, 32, 64);  a0 += __shfl_xor(a0, 16, 64);
    a1 += __shfl_xor(a1, 32, 64);  a1 += __shfl_xor(a1, 16, 64);
    a2 += __shfl_xor(a2, 32, 64);  a2 += __shfl_xor(a2, 16, 64);
    a3 += __shfl_xor(a3, 32, 64);  a3 += __shfl_xor(a3, 16, 64);
    a4 += __shfl_xor(a4, 32, 64);  a4 += __shfl_xor(a4, 16, 64);
    a5 += __shfl_xor(a5, 32, 64);  a5 += __shfl_xor(a5, 16, 64);
    a6 += __shfl_xor(a6, 32, 64);  a6 += __shfl_xor(a6, 16, 64);
    a7 += __shfl_xor(a7, 32, 64);  a7 += __shfl_xor(a7, 16, 64);
    if (lane < 16){
        uint4 o;
        o.x = packbf(a0, a1);  o.y = packbf(a2, a3);
        o.z = packbf(a4, a5);  o.w = packbf(a6, a7);
        Xa16[(size_t)n * 16 + fz] = o;                 // row-major 128 bf16
    }
}

// ---------------- FUSED double GEMM: X2 = (relu(Xa W1 + b1)) Wg + att logits.
// Wave owns 16 rows; h1 tile bounces through a wave-private XOR-swizzled LDS
// slab (no global h1 round-trip, no barrier). Swizzle: byte ^= (row&7)<<4 —
// linear [16][128]bf16 would be a 16-way bank conflict on ds_read_b128 (G4).
__global__ __launch_bounds__(512) void k_gemm2(
        const bf16* __restrict__ A, const bf16* __restrict__ W1p,
        const bf16* __restrict__ Wgp, const float* __restrict__ vecf,
        bf16* __restrict__ O, float2* __restrict__ aS, float2* __restrict__ aD){
    __shared__ __align__(16) unsigned char lds[8][4096];   // 16x128 bf16 per wave
    int wid  = threadIdx.x >> 6;
    int lane = threadIdx.x & 63;
    int r0 = blockIdx.x * 128 + wid * 16;
    int m = lane & 15, q = lane >> 4;
    unsigned char* myl = lds[wid];

    // GEMM1: h1 tile
    const bfrag* Ap = (const bfrag*)(A + (size_t)(r0 + m) * 128);
    bfrag af[4];
    #pragma unroll
    for (int kc = 0; kc < 4; ++kc) af[kc] = Ap[kc * 4 + q];

    #pragma unroll
    for (int ct = 0; ct < 8; ++ct){
        const bfrag* Bp = (const bfrag*)W1p + ct * 256 + lane;
        ffrag acc = {0.f, 0.f, 0.f, 0.f};
        #pragma unroll
        for (int kc = 0; kc < 4; ++kc)
            acc = __builtin_amdgcn_mfma_f32_16x16x32_bf16(af[kc], Bp[kc * 64], acc, 0, 0, 0);
        // relu + b1, store to swizzled LDS
        int col = ct * 16 + m;
        float bb = vecf[col];
        #pragma unroll
        for (int r = 0; r < 4; ++r){
            int row = q * 4 + r;
            unsigned byte = (unsigned)(row * 256 + col * 2) ^ ((row & 7) << 4);
            *(bf16*)(myl + byte) = __float2bfloat16(fmaxf(acc[r] + bb, 0.f));
        }
    }
    // re-read h1 tile in A-fragment layout (wave-private: in-order DS suffices)
    bfrag af2[4];
    #pragma unroll
    for (int kc = 0; kc < 4; ++kc){
        unsigned byte = (unsigned)(m * 256 + (kc * 32 + q * 8) * 2) ^ ((m & 7) << 4);
        af2[kc] = *(const bfrag*)(myl + byte);
    }

    // GEMM2: X2 = h1 Wg, interleaved store + att logits in-wave
    float ps0[4] = {0,0,0,0}, ps1[4] = {0,0,0,0};
    float pd0[4] = {0,0,0,0}, pd1[4] = {0,0,0,0};
    #pragma unroll
    for (int ct = 0; ct < 8; ++ct){
        const bfrag* Bp = (const bfrag*)Wgp + ct * 256 + lane;
        ffrag acc = {0.f, 0.f, 0.f, 0.f};
        #pragma unroll
        for (int kc = 0; kc < 4; ++kc)
            acc = __builtin_amdgcn_mfma_f32_16x16x32_bf16(af2[kc], Bp[kc * 64], acc, 0, 0, 0);
        const int h = ct >> 2;
        int f = (ct & 3) * 16 + m;
        float as_v = vecf[256 + h * 64 + f];
        float ad_v = vecf[384 + h * 64 + f];
        #pragma unroll
        for (int r = 0; r < 4; ++r){
            int row = r0 + q * 4 + r;
            if (row < N_NODES)
                O[(size_t)row * 128 + f * 2 + h] = __float2bfloat16(acc[r]);
            if (h == 0){ ps0[r] += acc[r] * as_v;  pd0[r] += acc[r] * ad_v; }
            else       { ps1[r] += acc[r] * as_v;  pd1[r] += acc[r] * ad_v; }
        }
    }
    #pragma unroll
    for (int off = 1; off < 16; off <<= 1){
        #pragma unroll
        for (int r = 0; r < 4; ++r){
            ps0[r] += __shfl_xor(ps0[r], off, 64);
            ps1[r] += __shfl_xor(ps1[r], off, 64);
            pd0[r] += __shfl_xor(pd0[r], off, 64);
            pd1[r] += __shfl_xor(pd1[r], off, 64);
        }
    }
    if (m == 0){
        #pragma unroll
        for (int r = 0; r < 4; ++r){
            int row = r0 + q * 4 + r;
            if (row < N_NODES){
                aS[row] = make_float2(ps0[r], ps1[r]);
                aD[row] = make_float2(pd0[r], pd1[r]);
            }
        }
    }
}

// ---------------- GAT aggregate: phase A (per-edge exp, lane-strided) ->
// phase B 4-way split (uint4 16B loads, 4 chains in flight) ----------------
__global__ __launch_bounds__(256) void k_gat(
        const uint4* __restrict__ X2v, const int* __restrict__ rp,
        const int2* __restrict__ ecr, const float2* __restrict__ a_src,
        const float2* __restrict__ a_dst, const float* __restrict__ vecf,
        uint2* __restrict__ Yu2){
    __shared__ int    scsr[SCAP];
    __shared__ float2 pe[SCAP];
    int n0 = blockIdx.x * 4;
    int b0 = rp[n0];
    int stot = min(rp[n0 + 4] - b0, SCAP);
    for (int i = threadIdx.x; i < stot; i += 256) scsr[i] = ecr[b0 + i].x;
    __syncthreads();

    int w = threadIdx.x >> 6, lane = threadIdx.x & 63;
    int q4 = lane >> 4, fz = lane & 15;
    int n = n0 + w;
    float2 ad = a_dst[n];
    int b = rp[n] - b0, e = rp[n + 1] - b0;
    int elim = min(e, stot);

    // Phase A: per-edge softmax numerators, one lane per edge
    for (int i = b + lane; i < elim; i += 64){
        float2 av = a_src[scsr[i]];
        float e0 = av.x + ad.x, e1 = av.y + ad.y;
        e0 = (e0 > 0.f) ? e0 : 0.2f * e0;              // leaky_relu 0.2
        e1 = (e1 > 0.f) ? e1 : 0.2f * e1;
        pe[i] = make_float2(__expf(e0), __expf(e1));
    }
    // intra-wave LDS write->read; compiler inserts lgkmcnt wait (same LDS object)

    // Phase B: 4-way split feature accumulation. X2 slots 8fz..8fz+7 =
    // features 4fz..4fz+3 x heads {0,1} (slot = f*2+h).
    float l0 = 0.f, l1 = 0.f;
    float o00=0,o01=0, o10=0,o11=0, o20=0,o21=0, o30=0,o31=0;   // o{k}{h}, f=4fz+k
    #pragma unroll 2
    for (int i = b + q4; i < elim; i += 4){
        float2 p = pe[i];
        uint4 v = X2v[(size_t)scsr[i] * 16 + fz];
        l0  += p.x;                  l1  += p.y;
        o00 += p.x * bfu2f_lo(v.x);  o01 += p.y * bfu2f_hi(v.x);
        o10 += p.x * bfu2f_lo(v.y);  o11 += p.y * bfu2f_hi(v.y);
        o20 += p.x * bfu2f_lo(v.z);  o21 += p.y * bfu2f_hi(v.z);
        o30 += p.x * bfu2f_lo(v.w);  o31 += p.y * bfu2f_hi(v.w);
    }
    int start = max(b, stot);
    int i0 = start + (((b + q4) - start) & 3);
    for (int i = i0; i < e; i += 4){                   // fallback (pathological degree)
        int s = ecr[b0 + i].x;
        float2 av = a_src[s];
        uint4 v = X2v[(size_t)s * 16 + fz];
        float e0 = av.x + ad.x, e1 = av.y + ad.y;
        e0 = (e0 > 0.f) ? e0 : 0.2f * e0;
        e1 = (e1 > 0.f) ? e1 : 0.2f * e1;
        float p0 = __expf(e0), p1 = __expf(e1);
        l0  += p0;                 l1  += p1;
        o00 += p0 * bfu2f_lo(v.x); o01 += p1 * bfu2f_hi(v.x);
        o10 += p0 * bfu2f_lo(v.y); o11 += p1 * bfu2f_hi(v.y);
        o20 += p0 * bfu2f_lo(v.z); o21 += p1 * bfu2f_hi(v.z);
        o30 += p0 * bfu2f_lo(v.w); o31 += p1 * bfu2f_hi(v.w);
    }
    l0  += __shfl_xor(l0, 32, 64);   l0  += __shfl_xor(l0, 16, 64);
    l1  += __shfl_xor(l1, 32, 64);   l1  += __shfl_xor(l1, 16, 64);
    o00 += __shfl_xor(o00, 32, 64);  o00 += __shfl_xor(o00, 16, 64);
    o01 += __shfl_xor(o01, 32, 64);  o01 += __shfl_xor(o01, 16, 64);
    o10 += __shfl_xor(o10, 32, 64);  o10 += __shfl_xor(o10, 16, 64);
    o11 += __shfl_xor(o11, 32, 64);  o11 += __shfl_xor(o11, 16, 64);
    o20 += __shfl_xor(o20, 32, 64);  o20 += __shfl_xor(o20, 16, 64);
    o21 += __shfl_xor(o21, 32, 64);  o21 += __shfl_xor(o21, 16, 64);
    o30 += __shfl_xor(o30, 32, 64);  o30 += __shfl_xor(o30, 16, 64);
    o31 += __shfl_xor(o31, 32, 64);  o31 += __shfl_xor(o31, 16, 64);
    if (lane < 16){
        float v0 = 0.5f * (o00 / l0 + o01 / l1) + vecf[128 + 4 * fz + 0];
        float v1 = 0.5f * (o10 / l0 + o11 / l1) + vecf[128 + 4 * fz + 1];
        float v2 = 0.5f * (o20 / l0 + o21 / l1) + vecf[128 + 4 * fz + 2];
        float v3 = 0.5f * (o30 / l0 + o31 / l1) + vecf[128 + 4 * fz + 3];
        v0 = (v0 > 0.f) ? v0 : expm1f(v0);             // ELU alpha=1
        v1 = (v1 > 0.f) ? v1 : expm1f(v1);
        v2 = (v2 > 0.f) ? v2 : expm1f(v2);
        v3 = (v3 > 0.f) ? v3 : expm1f(v3);
        Yu2[(size_t)n * 16 + fz] = make_uint2(packbf(v0, v1), packbf(v2, v3));
    }
}

// ---------------- gather_out: out = (A_hat Y) W3 + b3 — W3-GEMM fused into the
// epilogue by linearity (A_hat(Y W3) = (A_hat Y) W3): gather Y rows, stage agg
// + W3 in LDS, each lane computes one output feature.
__global__ __launch_bounds__(256) void k_gather_out(
        const uint2* __restrict__ Yu2, const int* __restrict__ rp,
        const int2* __restrict__ ecr, const bf16* __restrict__ W3r,
        const float* __restrict__ vecf, float* __restrict__ out){
    __shared__ int   scsr[SCAP];
    __shared__ float scf[SCAP];
    __shared__ bf16  sW3[4096];          // 8 KB, [k][f] row-major
    __shared__ float sagg[4][64];
    int n0 = blockIdx.x * 4;
    int b0 = rp[n0];
    int stot = min(rp[n0 + 4] - b0, SCAP);
    for (int i = threadIdx.x; i < stot; i += 256){
        int2 ev = ecr[b0 + i];
        scsr[i] = ev.x;
        scf[i]  = __int_as_float(ev.y);
    }
    {   // stage W3 (4096 bf16 = 512 uint4): 256 threads x 2
        uint4* d = (uint4*)sW3;
        const uint4* s = (const uint4*)W3r;
        d[threadIdx.x]       = s[threadIdx.x];
        d[threadIdx.x + 256] = s[threadIdx.x + 256];
    }
    __syncthreads();

    int w = threadIdx.x >> 6, lane = threadIdx.x & 63;
    int q4 = lane >> 4, fz = lane & 15;
    int n = n0 + w;
    float a0 = 0.f, a1 = 0.f, a2 = 0.f, a3 = 0.f;
    int b = rp[n] - b0, e = rp[n + 1] - b0;
    int elim = min(e, stot);
    #pragma unroll 2
    for (int i = b + q4; i < elim; i += 4){
        float c = scf[i];
        uint2 v = Yu2[(size_t)scsr[i] * 16 + fz];
        a0 += c * bfu2f_lo(v.x);  a1 += c * bfu2f_hi(v.x);
        a2 += c * bfu2f_lo(v.y);  a3 += c * bfu2f_hi(v.y);
    }
    int start = max(b, stot);
    int i0 = start + (((b + q4) - start) & 3);
    for (int i = i0; i < e; i += 4){                   // fallback
        int2 ev = ecr[b0 + i];
        float c = __int_as_float(ev.y);
        uint2 v = Yu2[(size_t)ev.x * 16 + fz];
        a0 += c * bfu2f_lo(v.x);  a1 += c * bfu2f_hi(v.x);
        a2 += c * bfu2f_lo(v.y);  a3 += c * bfu2f_hi(v.y);
    }
    a0 += __shfl_xor(a0, 32, 64);  a0 += __shfl_xor(a0, 16, 64);
    a1 += __shfl_xor(a1, 32, 64);  a1 += __shfl_xor(a1, 16, 64);
    a2 += __shfl_xor(a2, 32, 64);  a2 += __shfl_xor(a2, 16, 64);
    a3 += __shfl_xor(a3, 32, 64);  a3 += __shfl_xor(a3, 16, 64);
    if (lane < 16)
        ((float4*)sagg[w])[fz] = make_float4(a0, a1, a2, a3);
    // same-wave LDS write->read (k_gat Phase A/B precedent): lgkmcnt ordering

    // W3 apply: lane computes feature f = lane. agg broadcast (free),
    // sW3[k*64+f] = 128B/wave contiguous -> 2-way (free, m136).
    int f = lane;
    float acc = vecf[192 + f];                         // b3
    const float* ag = sagg[w];
    #pragma unroll 8
    for (int k = 0; k < 64; ++k)
        acc += ag[k] * __bfloat162float(sW3[k * 64 + f]);
    out[(size_t)n * 64 + f] = acc;
}

// ---------------- launch ----------------

extern "C" void kernel_launch(void* const* d_in, const int* in_sizes, int n_in,
                              void* d_out, int out_size, void* d_ws, size_t ws_size,
                              hipStream_t stream) {
    const void* x  = d_in[0];
    const int*  ei = (const int*)d_in[1];
    float* out = (float*)d_out;

    char* p = (char*)d_ws;
    auto alloc = [&](size_t bytes) -> void* {
        void* r = (void*)p;
        p += (bytes + 255) & ~(size_t)255;
        return r;
    };
    int*   deg      = (int*)  alloc((size_t)N_NODES * 4);
    int*   row_ptr  = (int*)  alloc((size_t)(N_NODES + 1) * 4);
    int*   blk      = (int*)  alloc(256 * 4);
    int2*  pkrk     = (int2*) alloc((size_t)E_TOT * 8);       // 6.8 MB (pack+rank)
    int2*  ecr      = (int2*) alloc((size_t)E_TOT * 8);       // 6.8 MB (src+coef)
    float* inv_sqrt = (float*)alloc((size_t)N_NODES * 4);
    float* a_src    = (float*)alloc((size_t)N_NODES * 2 * 4);
    float* a_dst    = (float*)alloc((size_t)N_NODES * 2 * 4);
    bf16*  W1p      = (bf16*) alloc(16384 * 2);
    bf16*  Wgp      = (bf16*) alloc(16384 * 2);
    bf16*  W3r      = (bf16*) alloc(4096 * 2);
    float* vecf     = (float*)alloc(512 * 4);
    bf16*  xb       = (bf16*) alloc((size_t)N_NODES * 128 * 2);  // 12.8 MB; dead after k_gather
    bf16*  XA       = (bf16*) alloc((size_t)N_NODES * 128 * 2);  // 12.8 MB (Xa -> X2)
    bf16*  Y        = (bf16*) alloc((size_t)N_NODES * 64 * 2);   //  6.4 MB

    const int NB_NODE = (N_NODES + 255) / 256;              // 196
    const int NXB     = (N_NODES * 32 + 255) / 256;         // 6250 (4 elems/thread)
    const int NB_CC   = NB_EDGE_C + 148 + NXB;              // merged convert+count grid
    const int NB_G128 = (N_NODES + 127) / 128;              // 391 (wave-owns-rows)

    hipMemsetAsync(deg, 0, (size_t)N_NODES * 4, stream);
    k_convert_count<<<NB_CC, 256, 0, stream>>>(x, d_in[2], d_in[4], d_in[8],
                                           d_in[3], d_in[7], d_in[9], d_in[5], d_in[6],
                                           W1p, Wgp, W3r, vecf, xb, ei, deg, pkrk);
    k_scanA<<<NB_NODE, 256, 0, stream>>>(deg, row_ptr, blk);
    k_scanC<<<NB_NODE, 256, 0, stream>>>(row_ptr, blk, deg, inv_sqrt, NB_NODE);
    k_fill<<<NB_EDGE_C, 256, 0, stream>>>(pkrk, row_ptr, inv_sqrt, ecr);

    k_gather<<<N_NODES / 4, 256, 0, stream>>>((const uint4*)xb, row_ptr, ecr,
                                              (uint4*)XA);
    k_gemm2<<<NB_G128, 512, 0, stream>>>(XA, W1p, Wgp, vecf, XA,
                                         (float2*)a_src, (float2*)a_dst);    // X2 + logits
    k_gat<<<N_NODES / 4, 256, 0, stream>>>((const uint4*)XA, row_ptr, ecr,
                                           (const float2*)a_src, (const float2*)a_dst,
                                           vecf, (uint2*)Y);
    k_gather_out<<<N_NODES / 4, 256, 0, stream>>>((const uint2*)Y, row_ptr, ecr,
                                                  W3r, vecf, out);
}

// Round 8
// 265.684 us; speedup vs baseline: 1.0102x; 1.0102x over previous
//
#include <hip/hip_runtime.h>
#include <hip/hip_bf16.h>
#include <math.h>

#define N_NODES 50000
#define E0      800000
#define E_TOT   (E0 + N_NODES)
#define SCAP    512
#define ECHUNK  (E_TOT / 4)                      // 212500 (divides exactly)
#define NB_CNT  ((ECHUNK + 255) / 256)           // 831
#define NB_EDGE_C ((E_TOT + 255) / 256)

using bf16 = __hip_bfloat16;
typedef __attribute__((ext_vector_type(8))) short bfrag;   // 8 bf16 (4 VGPRs)
typedef __attribute__((ext_vector_type(4))) float ffrag;   // 4 fp32 acc

static __device__ __forceinline__ float bfu2f_lo(unsigned u){ return __uint_as_float(u << 16); }
static __device__ __forceinline__ float bfu2f_hi(unsigned u){ return __uint_as_float(u & 0xffff0000u); }

static __device__ __forceinline__ unsigned packbf(float a, float b){
    bf16 x = __float2bfloat16(a), y = __float2bfloat16(b);
    unsigned short ux = *reinterpret_cast<unsigned short*>(&x);
    unsigned short uy = *reinterpret_cast<unsigned short*>(&y);
    return ((unsigned)uy << 16) | ux;
}

// per-wave dtype detects (one coalesced load + ballot)
static __device__ __forceinline__ int detect_f32(const unsigned* xu){
    int lane = threadIdx.x & 63;
    unsigned ex = (xu[lane] >> 7) & 0xFF;
    return (__ballot(ex < 100 || ex > 140) != 0ULL);
}
static __device__ __forceinline__ int detect_i32(const int* ei){
    int lane = threadIdx.x & 63;
    return (__ballot(ei[2 * lane + 1] != 0) != 0ULL);
}

static __device__ __forceinline__ float ldany(const void* p, int i, int isf32){
    return isf32 ? ((const float*)p)[i] : __bfloat162float(((const bf16*)p)[i]);
}

static __device__ __forceinline__ int load_dst(const int* ei, int e, int is32){
    if (e >= E0) return e - E0;
    return is32 ? ei[E0 + e] : (int)((const long long*)ei)[E0 + e];
}
static __device__ __forceinline__ int load_src(const int* ei, int e, int is32){
    if (e >= E0) return e - E0;
    return is32 ? ei[e] : (int)((const long long*)ei)[e];
}

// ---------------- MERGED convert + count: one grid, block-range split.
// Count part: 4 edges/thread (chunk-strided, coalesced), explicitly staged
// loads -> 4 independent atomic-with-return -> stores. If the 35us count cost
// is atomic-latency EXPOSURE, 4x ILP quarters the stalls; if coherence-point
// THROUGHPUT, this is neutral (discriminating experiment).
// deg must be zeroed BEFORE this kernel (hipMemsetAsync in launch).
// vecf: b1 @0(128), bg @128(64), b3 @192(64), att_s @256(128), att_d @384(128)
__global__ void k_convert_count(const void* __restrict__ xv,
                          const void* W1, const void* Wg, const void* W3,
                          const void* b1, const void* bg, const void* b3,
                          const void* as_, const void* ad_,
                          bf16* __restrict__ W1p, bf16* __restrict__ Wgp,
                          bf16* __restrict__ W3r, float* __restrict__ vecf,
                          bf16* __restrict__ xb,
                          const int* __restrict__ ei, int* __restrict__ deg,
                          int2* __restrict__ pkrk){
    int blk = blockIdx.x, t = threadIdx.x;
    if (blk < NB_CNT){                        // ---- count part: 4 edges/thread ----
        int is32 = detect_i32(ei);
        int e0 = blk * 256 + t;
        if (e0 >= ECHUNK) return;
        int d[4], s[4];
        #pragma unroll
        for (int k = 0; k < 4; ++k){
            int e = e0 + k * ECHUNK;
            d[k] = load_dst(ei, e, is32);
            s[k] = load_src(ei, e, is32);
        }
        int r[4];
        #pragma unroll
        for (int k = 0; k < 4; ++k){
            bool ok = (unsigned)d[k] < N_NODES && (unsigned)s[k] < N_NODES;
            r[k] = ok ? atomicAdd(&deg[d[k]], 1) : 0;
            if (!ok) d[k] = -1;
        }
        #pragma unroll
        for (int k = 0; k < 4; ++k){
            int e = e0 + k * ECHUNK;
            pkrk[e] = (d[k] < 0) ? make_int2(-1, 0)
                                 : make_int2((s[k] << 16) | d[k], r[k]);
        }
        return;
    }
    int b = blk - NB_CNT;                     // ---- convert part ----
    int isf = detect_f32((const unsigned*)xv);
    if (b >= 148){
        int i = (b - 148) * 256 + t;               // quad index
        if (i < N_NODES * 32){
            if (isf){
                float4 v = ((const float4*)xv)[i];
                ((uint2*)xb)[i] = make_uint2(packbf(v.x, v.y), packbf(v.z, v.w));
            } else {
                ((uint2*)xb)[i] = ((const uint2*)xv)[i];   // already bf16: copy
            }
        }
        return;
    }
    if (b < 16){                              // W3 plain row-major copy: 4096 elems
        int dd = b * 256 + t;
        W3r[dd] = __float2bfloat16(ldany(W3, dd, isf));
    }
    else if (b < 18){
        int i = (b - 16) * 256 + t;     // 0..511
        float v;
        if      (i < 128) v = ldany(b1,  i,       isf);
        else if (i < 192) v = ldany(bg,  i - 128, isf);
        else if (i < 256) v = ldany(b3,  i - 192, isf);
        else if (i < 384) v = ldany(as_, i - 256, isf);
        else              v = ldany(ad_, i - 384, isf);
        vecf[i] = v;
    } else {
        int d = (b - 18) * 256 + t;          // 0..16383 per W, two Ws
        const void* Wsrc = (d < 16384) ? W1 : Wg;
        bf16* Wdst = (d < 16384) ? W1p : Wgp;
        int dd = d & 16383;
        int j  = dd & 7;
        int L  = (dd >> 3) & 63;
        int kc = (dd >> 9) & 3;
        int ct = dd >> 11;
        int k = kc * 32 + ((L >> 4) << 3) + j;
        int n = ct * 16 + (L & 15);
        Wdst[dd] = __float2bfloat16(ldany(Wsrc, k * 128 + n, isf));
    }
}

__global__ void k_scanA(const int* __restrict__ deg, int* __restrict__ tmp, int* __restrict__ blk){
    __shared__ int s[256];
    int t = threadIdx.x;
    int i = blockIdx.x * 256 + t;
    int v = (i < N_NODES) ? deg[i] : 0;
    s[t] = v; __syncthreads();
    for (int off = 1; off < 256; off <<= 1){
        int x = (t >= off) ? s[t - off] : 0;
        __syncthreads();
        s[t] += x;
        __syncthreads();
    }
    if (t == 255) blk[blockIdx.x] = s[255];
    if (i < N_NODES) tmp[i] = s[t] - v;
}

// scanC with inlined cross-block prefix (each block reduces blk[0..B-1] itself)
__global__ void k_scanC(int* __restrict__ row_ptr, const int* __restrict__ blk,
                        const int* __restrict__ deg, float* __restrict__ inv_sqrt,
                        int nb){
    __shared__ int s[256];
    int t = threadIdx.x;
    int B = blockIdx.x;
    s[t] = (t < nb && t < B) ? blk[t] : 0;
    __syncthreads();
    for (int off = 128; off; off >>= 1){
        if (t < off) s[t] += s[t + off];
        __syncthreads();
    }
    int base = s[0];
    int i = B * 256 + t;
    if (i < N_NODES){
        row_ptr[i] += base;
        int d = deg[i];
        inv_sqrt[i] = (d > 0) ? rsqrtf((float)d) : 0.0f;
    }
    if (i == 0) row_ptr[N_NODES] = E_TOT;
}

// fill: NO atomics, no int64 re-read; one streaming int2 read + one scattered
// int2 store per edge.
__global__ void k_fill(const int2* __restrict__ pkrk, const int* __restrict__ row_ptr,
                       const float* __restrict__ isq, int2* __restrict__ ecr){
    int e = blockIdx.x * blockDim.x + threadIdx.x;
    if (e >= E_TOT) return;
    int2 pr = pkrk[e];
    unsigned pk = (unsigned)pr.x;
    if (pk == 0xFFFFFFFFu) return;
    int dst = pk & 0xFFFF;
    int src = pk >> 16;
    int pos = row_ptr[dst] + pr.y;
    float c = isq[dst] * isq[src];
    ecr[pos] = make_int2(src, __float_as_int(c));
}

// ---------------- gather: Xa = A_hat x — 4-way split wave; uint4 loads ----------------
__global__ __launch_bounds__(256) void k_gather(
        const uint4* __restrict__ xb16, const int* __restrict__ rp,
        const int2* __restrict__ ecr, uint4* __restrict__ Xa16){
    __shared__ int   scsr[SCAP];
    __shared__ float scf[SCAP];
    int n0 = blockIdx.x * 4;
    int b0 = rp[n0];
    int stot = min(rp[n0 + 4] - b0, SCAP);
    for (int i = threadIdx.x; i < stot; i += 256){
        int2 ev = ecr[b0 + i];
        scsr[i] = ev.x;
        scf[i]  = __int_as_float(ev.y);
    }
    __syncthreads();

    int w = threadIdx.x >> 6, lane = threadIdx.x & 63;
    int q4 = lane >> 4, fz = lane & 15;
    int n = n0 + w;
    float a0=0,a1=0,a2=0,a3=0,a4=0,a5=0,a6=0,a7=0;
    int b = rp[n] - b0, e = rp[n + 1] - b0;
    int elim = min(e, stot);
    #pragma unroll 2
    for (int i = b + q4; i < elim; i += 4){
        int s = scsr[i];
        float c = scf[i];
        uint4 v = xb16[(size_t)s * 16 + fz];
        a0 += c * bfu2f_lo(v.x);  a1 += c * bfu2f_hi(v.x);
        a2 += c * bfu2f_lo(v.y);  a3 += c * bfu2f_hi(v.y);
        a4 += c * bfu2f_lo(v.z);  a5 += c * bfu2f_hi(v.z);
        a6 += c * bfu2f_lo(v.w);  a7 += c * bfu2f_hi(v.w);
    }
    int start = max(b, stot);
    int i0 = start + (((b + q4) - start) & 3);         // keep i ≡ b+q4 (mod 4)
    for (int i = i0; i < e; i += 4){                   // fallback (pathological degree)
        int2 ev = ecr[b0 + i];
        float c = __int_as_float(ev.y);
        uint4 v = xb16[(size_t)ev.x * 16 + fz];
        a0 += c * bfu2f_lo(v.x);  a1 += c * bfu2f_hi(v.x);
        a2 += c * bfu2f_lo(v.y);  a3 += c * bfu2f_hi(v.y);
        a4 += c * bfu2f_lo(v.z);  a5 += c * bfu2f_hi(v.z);
        a6 += c * bfu2f_lo(v.w);  a7 += c * bfu2f_hi(v.w);
    }
    a0 += __shfl_xor(a0, 32, 64);  a0 += __shfl_xor(a0, 16, 64);
    a1 += __shfl_xor(a1, 32, 64);  a1 += __shfl_xor(a1, 16, 64);
    a2 += __shfl_xor(a2, 32, 64);  a2 += __shfl_xor(a2, 16, 64);
    a3 += __shfl_xor(a3, 32, 64);  a3 += __shfl_xor(a3, 16, 64);
    a4 += __shfl_xor(a4, 32, 64);  a4 += __shfl_xor(a4, 16, 64);
    a5 += __shfl_xor(a5, 32, 64);  a5 += __shfl_xor(a5, 16, 64);
    a6 += __shfl_xor(a6, 32, 64);  a6 += __shfl_xor(a6, 16, 64);
    a7 += __shfl_xor(a7, 32, 64);  a7 += __shfl_xor(a7, 16, 64);
    if (lane < 16){
        uint4 o;
        o.x = packbf(a0, a1);  o.y = packbf(a2, a3);
        o.z = packbf(a4, a5);  o.w = packbf(a6, a7);
        Xa16[(size_t)n * 16 + fz] = o;                 // row-major 128 bf16
    }
}

// ---------------- FUSED double GEMM: X2 = (relu(Xa W1 + b1)) Wg + att logits.
// Wave owns 16 rows; h1 tile bounces through a wave-private XOR-swizzled LDS
// slab (no global h1 round-trip, no barrier). Swizzle: byte ^= (row&7)<<4 —
// linear [16][128]bf16 would be a 16-way bank conflict on ds_read_b128 (G4).
__global__ __launch_bounds__(512) void k_gemm2(
        const bf16* __restrict__ A, const bf16* __restrict__ W1p,
        const bf16* __restrict__ Wgp, const float* __restrict__ vecf,
        bf16* __restrict__ O, float2* __restrict__ aS, float2* __restrict__ aD){
    __shared__ __align__(16) unsigned char lds[8][4096];   // 16x128 bf16 per wave
    int wid  = threadIdx.x >> 6;
    int lane = threadIdx.x & 63;
    int r0 = blockIdx.x * 128 + wid * 16;
    int m = lane & 15, q = lane >> 4;
    unsigned char* myl = lds[wid];

    // GEMM1: h1 tile
    const bfrag* Ap = (const bfrag*)(A + (size_t)(r0 + m) * 128);
    bfrag af[4];
    #pragma unroll
    for (int kc = 0; kc < 4; ++kc) af[kc] = Ap[kc * 4 + q];

    #pragma unroll
    for (int ct = 0; ct < 8; ++ct){
        const bfrag* Bp = (const bfrag*)W1p + ct * 256 + lane;
        ffrag acc = {0.f, 0.f, 0.f, 0.f};
        #pragma unroll
        for (int kc = 0; kc < 4; ++kc)
            acc = __builtin_amdgcn_mfma_f32_16x16x32_bf16(af[kc], Bp[kc * 64], acc, 0, 0, 0);
        // relu + b1, store to swizzled LDS
        int col = ct * 16 + m;
        float bb = vecf[col];
        #pragma unroll
        for (int r = 0; r < 4; ++r){
            int row = q * 4 + r;
            unsigned byte = (unsigned)(row * 256 + col * 2) ^ ((row & 7) << 4);
            *(bf16*)(myl + byte) = __float2bfloat16(fmaxf(acc[r] + bb, 0.f));
        }
    }
    // re-read h1 tile in A-fragment layout (wave-private: in-order DS suffices)
    bfrag af2[4];
    #pragma unroll
    for (int kc = 0; kc < 4; ++kc){
        unsigned byte = (unsigned)(m * 256 + (kc * 32 + q * 8) * 2) ^ ((m & 7) << 4);
        af2[kc] = *(const bfrag*)(myl + byte);
    }

    // GEMM2: X2 = h1 Wg, interleaved store + att logits in-wave
    float ps0[4] = {0,0,0,0}, ps1[4] = {0,0,0,0};
    float pd0[4] = {0,0,0,0}, pd1[4] = {0,0,0,0};
    #pragma unroll
    for (int ct = 0; ct < 8; ++ct){
        const bfrag* Bp = (const bfrag*)Wgp + ct * 256 + lane;
        ffrag acc = {0.f, 0.f, 0.f, 0.f};
        #pragma unroll
        for (int kc = 0; kc < 4; ++kc)
            acc = __builtin_amdgcn_mfma_f32_16x16x32_bf16(af2[kc], Bp[kc * 64], acc, 0, 0, 0);
        const int h = ct >> 2;
        int f = (ct & 3) * 16 + m;
        float as_v = vecf[256 + h * 64 + f];
        float ad_v = vecf[384 + h * 64 + f];
        #pragma unroll
        for (int r = 0; r < 4; ++r){
            int row = r0 + q * 4 + r;
            if (row < N_NODES)
                O[(size_t)row * 128 + f * 2 + h] = __float2bfloat16(acc[r]);
            if (h == 0){ ps0[r] += acc[r] * as_v;  pd0[r] += acc[r] * ad_v; }
            else       { ps1[r] += acc[r] * as_v;  pd1[r] += acc[r] * ad_v; }
        }
    }
    #pragma unroll
    for (int off = 1; off < 16; off <<= 1){
        #pragma unroll
        for (int r = 0; r < 4; ++r){
            ps0[r] += __shfl_xor(ps0[r], off, 64);
            ps1[r] += __shfl_xor(ps1[r], off, 64);
            pd0[r] += __shfl_xor(pd0[r], off, 64);
            pd1[r] += __shfl_xor(pd1[r], off, 64);
        }
    }
    if (m == 0){
        #pragma unroll
        for (int r = 0; r < 4; ++r){
            int row = r0 + q * 4 + r;
            if (row < N_NODES){
                aS[row] = make_float2(ps0[r], ps1[r]);
                aD[row] = make_float2(pd0[r], pd1[r]);
            }
        }
    }
}

// ---------------- GAT aggregate: phase A (per-edge exp, lane-strided) ->
// phase B 4-way split (uint4 16B loads, 4 chains in flight) ----------------
__global__ __launch_bounds__(256) void k_gat(
        const uint4* __restrict__ X2v, const int* __restrict__ rp,
        const int2* __restrict__ ecr, const float2* __restrict__ a_src,
        const float2* __restrict__ a_dst, const float* __restrict__ vecf,
        uint2* __restrict__ Yu2){
    __shared__ int    scsr[SCAP];
    __shared__ float2 pe[SCAP];
    int n0 = blockIdx.x * 4;
    int b0 = rp[n0];
    int stot = min(rp[n0 + 4] - b0, SCAP);
    for (int i = threadIdx.x; i < stot; i += 256) scsr[i] = ecr[b0 + i].x;
    __syncthreads();

    int w = threadIdx.x >> 6, lane = threadIdx.x & 63;
    int q4 = lane >> 4, fz = lane & 15;
    int n = n0 + w;
    float2 ad = a_dst[n];
    int b = rp[n] - b0, e = rp[n + 1] - b0;
    int elim = min(e, stot);

    // Phase A: per-edge softmax numerators, one lane per edge
    for (int i = b + lane; i < elim; i += 64){
        float2 av = a_src[scsr[i]];
        float e0 = av.x + ad.x, e1 = av.y + ad.y;
        e0 = (e0 > 0.f) ? e0 : 0.2f * e0;              // leaky_relu 0.2
        e1 = (e1 > 0.f) ? e1 : 0.2f * e1;
        pe[i] = make_float2(__expf(e0), __expf(e1));
    }
    // intra-wave LDS write->read; compiler inserts lgkmcnt wait (same LDS object)

    // Phase B: 4-way split feature accumulation. X2 slots 8fz..8fz+7 =
    // features 4fz..4fz+3 x heads {0,1} (slot = f*2+h).
    float l0 = 0.f, l1 = 0.f;
    float o00=0,o01=0, o10=0,o11=0, o20=0,o21=0, o30=0,o31=0;   // o{k}{h}, f=4fz+k
    #pragma unroll 2
    for (int i = b + q4; i < elim; i += 4){
        float2 p = pe[i];
        uint4 v = X2v[(size_t)scsr[i] * 16 + fz];
        l0  += p.x;                  l1  += p.y;
        o00 += p.x * bfu2f_lo(v.x);  o01 += p.y * bfu2f_hi(v.x);
        o10 += p.x * bfu2f_lo(v.y);  o11 += p.y * bfu2f_hi(v.y);
        o20 += p.x * bfu2f_lo(v.z);  o21 += p.y * bfu2f_hi(v.z);
        o30 += p.x * bfu2f_lo(v.w);  o31 += p.y * bfu2f_hi(v.w);
    }
    int start = max(b, stot);
    int i0 = start + (((b + q4) - start) & 3);
    for (int i = i0; i < e; i += 4){                   // fallback (pathological degree)
        int s = ecr[b0 + i].x;
        float2 av = a_src[s];
        uint4 v = X2v[(size_t)s * 16 + fz];
        float e0 = av.x + ad.x, e1 = av.y + ad.y;
        e0 = (e0 > 0.f) ? e0 : 0.2f * e0;
        e1 = (e1 > 0.f) ? e1 : 0.2f * e1;
        float p0 = __expf(e0), p1 = __expf(e1);
        l0  += p0;                 l1  += p1;
        o00 += p0 * bfu2f_lo(v.x); o01 += p1 * bfu2f_hi(v.x);
        o10 += p0 * bfu2f_lo(v.y); o11 += p1 * bfu2f_hi(v.y);
        o20 += p0 * bfu2f_lo(v.z); o21 += p1 * bfu2f_hi(v.z);
        o30 += p0 * bfu2f_lo(v.w); o31 += p1 * bfu2f_hi(v.w);
    }
    l0  += __shfl_xor(l0, 32, 64);   l0  += __shfl_xor(l0, 16, 64);
    l1  += __shfl_xor(l1, 32, 64);   l1  += __shfl_xor(l1, 16, 64);
    o00 += __shfl_xor(o00, 32, 64);  o00 += __shfl_xor(o00, 16, 64);
    o01 += __shfl_xor(o01, 32, 64);  o01 += __shfl_xor(o01, 16, 64);
    o10 += __shfl_xor(o10, 32, 64);  o10 += __shfl_xor(o10, 16, 64);
    o11 += __shfl_xor(o11, 32, 64);  o11 += __shfl_xor(o11, 16, 64);
    o20 += __shfl_xor(o20, 32, 64);  o20 += __shfl_xor(o20, 16, 64);
    o21 += __shfl_xor(o21, 32, 64);  o21 += __shfl_xor(o21, 16, 64);
    o30 += __shfl_xor(o30, 32, 64);  o30 += __shfl_xor(o30, 16, 64);
    o31 += __shfl_xor(o31, 32, 64);  o31 += __shfl_xor(o31, 16, 64);
    if (lane < 16){
        float v0 = 0.5f * (o00 / l0 + o01 / l1) + vecf[128 + 4 * fz + 0];
        float v1 = 0.5f * (o10 / l0 + o11 / l1) + vecf[128 + 4 * fz + 1];
        float v2 = 0.5f * (o20 / l0 + o21 / l1) + vecf[128 + 4 * fz + 2];
        float v3 = 0.5f * (o30 / l0 + o31 / l1) + vecf[128 + 4 * fz + 3];
        v0 = (v0 > 0.f) ? v0 : expm1f(v0);             // ELU alpha=1
        v1 = (v1 > 0.f) ? v1 : expm1f(v1);
        v2 = (v2 > 0.f) ? v2 : expm1f(v2);
        v3 = (v3 > 0.f) ? v3 : expm1f(v3);
        Yu2[(size_t)n * 16 + fz] = make_uint2(packbf(v0, v1), packbf(v2, v3));
    }
}

// ---------------- gather_out: out = (A_hat Y) W3 + b3 — W3-GEMM fused into the
// epilogue by linearity (A_hat(Y W3) = (A_hat Y) W3): gather Y rows, stage agg
// + W3 in LDS, each lane computes one output feature.
__global__ __launch_bounds__(256) void k_gather_out(
        const uint2* __restrict__ Yu2, const int* __restrict__ rp,
        const int2* __restrict__ ecr, const bf16* __restrict__ W3r,
        const float* __restrict__ vecf, float* __restrict__ out){
    __shared__ int   scsr[SCAP];
    __shared__ float scf[SCAP];
    __shared__ bf16  sW3[4096];          // 8 KB, [k][f] row-major
    __shared__ float sagg[4][64];
    int n0 = blockIdx.x * 4;
    int b0 = rp[n0];
    int stot = min(rp[n0 + 4] - b0, SCAP);
    for (int i = threadIdx.x; i < stot; i += 256){
        int2 ev = ecr[b0 + i];
        scsr[i] = ev.x;
        scf[i]  = __int_as_float(ev.y);
    }
    {   // stage W3 (4096 bf16 = 512 uint4): 256 threads x 2
        uint4* d = (uint4*)sW3;
        const uint4* s = (const uint4*)W3r;
        d[threadIdx.x]       = s[threadIdx.x];
        d[threadIdx.x + 256] = s[threadIdx.x + 256];
    }
    __syncthreads();

    int w = threadIdx.x >> 6, lane = threadIdx.x & 63;
    int q4 = lane >> 4, fz = lane & 15;
    int n = n0 + w;
    float a0 = 0.f, a1 = 0.f, a2 = 0.f, a3 = 0.f;
    int b = rp[n] - b0, e = rp[n + 1] - b0;
    int elim = min(e, stot);
    #pragma unroll 2
    for (int i = b + q4; i < elim; i += 4){
        float c = scf[i];
        uint2 v = Yu2[(size_t)scsr[i] * 16 + fz];
        a0 += c * bfu2f_lo(v.x);  a1 += c * bfu2f_hi(v.x);
        a2 += c * bfu2f_lo(v.y);  a3 += c * bfu2f_hi(v.y);
    }
    int start = max(b, stot);
    int i0 = start + (((b + q4) - start) & 3);
    for (int i = i0; i < e; i += 4){                   // fallback
        int2 ev = ecr[b0 + i];
        float c = __int_as_float(ev.y);
        uint2 v = Yu2[(size_t)ev.x * 16 + fz];
        a0 += c * bfu2f_lo(v.x);  a1 += c * bfu2f_hi(v.x);
        a2 += c * bfu2f_lo(v.y);  a3 += c * bfu2f_hi(v.y);
    }
    a0 += __shfl_xor(a0, 32, 64);  a0 += __shfl_xor(a0, 16, 64);
    a1 += __shfl_xor(a1, 32, 64);  a1 += __shfl_xor(a1, 16, 64);
    a2 += __shfl_xor(a2, 32, 64);  a2 += __shfl_xor(a2, 16, 64);
    a3 += __shfl_xor(a3, 32, 64);  a3 += __shfl_xor(a3, 16, 64);
    if (lane < 16)
        ((float4*)sagg[w])[fz] = make_float4(a0, a1, a2, a3);
    // same-wave LDS write->read (k_gat Phase A/B precedent): lgkmcnt ordering

    // W3 apply: lane computes feature f = lane. agg broadcast (free),
    // sW3[k*64+f] = 128B/wave contiguous -> 2-way (free, m136).
    int f = lane;
    float acc = vecf[192 + f];                         // b3
    const float* ag = sagg[w];
    #pragma unroll 8
    for (int k = 0; k < 64; ++k)
        acc += ag[k] * __bfloat162float(sW3[k * 64 + f]);
    out[(size_t)n * 64 + f] = acc;
}

// ---------------- launch ----------------

extern "C" void kernel_launch(void* const* d_in, const int* in_sizes, int n_in,
                              void* d_out, int out_size, void* d_ws, size_t ws_size,
                              hipStream_t stream) {
    const void* x  = d_in[0];
    const int*  ei = (const int*)d_in[1];
    float* out = (float*)d_out;

    char* p = (char*)d_ws;
    auto alloc = [&](size_t bytes) -> void* {
        void* r = (void*)p;
        p += (bytes + 255) & ~(size_t)255;
        return r;
    };
    int*   deg      = (int*)  alloc((size_t)N_NODES * 4);
    int*   row_ptr  = (int*)  alloc((size_t)(N_NODES + 1) * 4);
    int*   blk      = (int*)  alloc(256 * 4);
    int2*  pkrk     = (int2*) alloc((size_t)E_TOT * 8);       // 6.8 MB (pack+rank)
    int2*  ecr      = (int2*) alloc((size_t)E_TOT * 8);       // 6.8 MB (src+coef)
    float* inv_sqrt = (float*)alloc((size_t)N_NODES * 4);
    float* a_src    = (float*)alloc((size_t)N_NODES * 2 * 4);
    float* a_dst    = (float*)alloc((size_t)N_NODES * 2 * 4);
    bf16*  W1p      = (bf16*) alloc(16384 * 2);
    bf16*  Wgp      = (bf16*) alloc(16384 * 2);
    bf16*  W3r      = (bf16*) alloc(4096 * 2);
    float* vecf     = (float*)alloc(512 * 4);
    bf16*  xb       = (bf16*) alloc((size_t)N_NODES * 128 * 2);  // 12.8 MB; dead after k_gather
    bf16*  XA       = (bf16*) alloc((size_t)N_NODES * 128 * 2);  // 12.8 MB (Xa -> X2)
    bf16*  Y        = (bf16*) alloc((size_t)N_NODES * 64 * 2);   //  6.4 MB

    const int NB_NODE = (N_NODES + 255) / 256;              // 196
    const int NXB     = (N_NODES * 32 + 255) / 256;         // 6250 (4 elems/thread)
    const int NB_CC   = NB_CNT + 148 + NXB;                 // merged convert+count grid
    const int NB_G128 = (N_NODES + 127) / 128;              // 391 (wave-owns-rows)

    hipMemsetAsync(deg, 0, (size_t)N_NODES * 4, stream);
    k_convert_count<<<NB_CC, 256, 0, stream>>>(x, d_in[2], d_in[4], d_in[8],
                                           d_in[3], d_in[7], d_in[9], d_in[5], d_in[6],
                                           W1p, Wgp, W3r, vecf, xb, ei, deg, pkrk);
    k_scanA<<<NB_NODE, 256, 0, stream>>>(deg, row_ptr, blk);
    k_scanC<<<NB_NODE, 256, 0, stream>>>(row_ptr, blk, deg, inv_sqrt, NB_NODE);
    k_fill<<<NB_EDGE_C, 256, 0, stream>>>(pkrk, row_ptr, inv_sqrt, ecr);

    k_gather<<<N_NODES / 4, 256, 0, stream>>>((const uint4*)xb, row_ptr, ecr,
                                              (uint4*)XA);
    k_gemm2<<<NB_G128, 512, 0, stream>>>(XA, W1p, Wgp, vecf, XA,
                                         (float2*)a_src, (float2*)a_dst);    // X2 + logits
    k_gat<<<N_NODES / 4, 256, 0, stream>>>((const uint4*)XA, row_ptr, ecr,
                                           (const float2*)a_src, (const float2*)a_dst,
                                           vecf, (uint2*)Y);
    k_gather_out<<<N_NODES / 4, 256, 0, stream>>>((const uint2*)Y, row_ptr, ecr,
                                                  W3r, vecf, out);
}